// Round 1
// baseline (1051.665 us; speedup 1.0000x reference)
//
#include <hip/hip_runtime.h>

typedef short v8s __attribute__((ext_vector_type(8)));
typedef float v4f __attribute__((ext_vector_type(4)));

__device__ __forceinline__ unsigned short f2bf(float x) {
  union { float f; unsigned int u; } c; c.f = x;
  unsigned int u = c.u;
  unsigned int r = (u + 0x7fffu + ((u >> 16) & 1u)) >> 16;
  return (unsigned short)r;
}

__global__ void zero_f4(float4* __restrict__ p, int n4) {
  int i = blockIdx.x * 256 + threadIdx.x;
  if (i < n4) p[i] = make_float4(0.f, 0.f, 0.f, 0.f);
}

__global__ void bn_fold_k(const float* __restrict__ g1, const float* __restrict__ be1,
                          const float* __restrict__ rm1, const float* __restrict__ rv1,
                          const float* __restrict__ g2, const float* __restrict__ be2,
                          const float* __restrict__ rm2, const float* __restrict__ rv2,
                          float* __restrict__ s1, float* __restrict__ t1,
                          float* __restrict__ s2, float* __restrict__ t2) {
  int i = threadIdx.x;
  if (i < 128) {
    float sv = g1[i] * rsqrtf(rv1[i] + 1e-5f);
    s1[i] = sv; t1[i] = be1[i] - rm1[i] * sv;
    float sw = g2[i] * rsqrtf(rv2[i] + 1e-5f);
    s2[i] = sw; t2[i] = be2[i] - rm2[i] * sw;
  }
}

// Pack stacked [W_l; W_r] (K = 2F, zero-padded to KC*32) into B-fragment layout:
// wpk[kc*4096 + n*32 + kk]  (kk = k within chunk), bf16.
template<int F, int KC>
__global__ void pack_w_k(const float* __restrict__ Wl, const float* __restrict__ Wr,
                         unsigned short* __restrict__ wpk) {
  int i = blockIdx.x * 256 + threadIdx.x;
  if (i >= KC * 4096) return;
  int kk = i & 31, n = (i >> 5) & 127, kc = i >> 12;
  int k = kc * 32 + kk;
  float v = 0.f;
  if (k < F) v = Wl[k * 128 + n];
  else if (k < 2 * F) v = Wr[(k - F) * 128 + n];
  wpk[i] = f2bf(v);
}

__global__ void deg_k(const int* __restrict__ dst, float* __restrict__ deg, int E) {
  int i = blockIdx.x * 256 + threadIdx.x;
  if (i < E) unsafeAtomicAdd(&deg[dst[i]], 1.0f);
}

template<int F>
__global__ void scatter_k(const float* __restrict__ xin, const int* __restrict__ src,
                          const int* __restrict__ dst, float* __restrict__ agg, int E) {
  int i = blockIdx.x * 256 + threadIdx.x;
  int total = E * F;
  if (i >= total) return;
  int e = i / F;
  int f = i - e * F;
  unsafeAtomicAdd(&agg[dst[e] * F + f], xin[src[e] * F + f]);
}

// Fused: out[n][j] = relu( ((mean[n]|x[n]) . Wpk[:,j] + b[j]) * s[j] + t[j] )
// A staged to LDS as bf16, K stacked = 2F padded to KC*32.
template<int F, int KC>
__global__ __launch_bounds__(256) void gemm_k(
    const float* __restrict__ agg, const float* __restrict__ deg,
    const float* __restrict__ xin, const unsigned short* __restrict__ wpk,
    const float* __restrict__ bias, const float* __restrict__ sc,
    const float* __restrict__ tc, float* __restrict__ out, int N) {
  constexpr int KP = KC * 32;
  constexpr int LDA = KP + 8;
  __shared__ __align__(16) unsigned short a_s[64][LDA];
  const int tid = threadIdx.x;
  const int node0 = blockIdx.x * 64;

  { // stage [mean | x] as bf16; 8 groups of 32 lanes, each group does 8 rows
    const int g = tid >> 5, l = tid & 31;
    for (int r8 = 0; r8 < 8; ++r8) {
      const int row = r8 * 8 + g;
      const int node = node0 + row;
      if (node < N) {
        const float inv = 1.0f / fmaxf(deg[node], 1.0f);
        const float* ap = agg + (long)node * F;
        const float* xp = xin + (long)node * F;
        for (int k = l; k < F; k += 32) {
          a_s[row][k]     = f2bf(ap[k] * inv);
          a_s[row][F + k] = f2bf(xp[k]);
        }
      } else {
        for (int k = l; k < 2 * F; k += 32) a_s[row][k] = 0;
      }
      for (int k = 2 * F + l; k < KP; k += 32) a_s[row][k] = 0;
    }
  }
  __syncthreads();

  const int wave = tid >> 6, lane = tid & 63;
  const int quad = lane >> 4, l16 = lane & 15;
  const int nt0 = wave * 2;  // each wave: 2 n-tiles x 4 m-tiles of 16x16
  v4f acc[4][2];
#pragma unroll
  for (int mt = 0; mt < 4; ++mt)
#pragma unroll
    for (int nt = 0; nt < 2; ++nt) acc[mt][nt] = (v4f){0.f, 0.f, 0.f, 0.f};

#pragma unroll
  for (int kc = 0; kc < KC; ++kc) {
    v8s bf[2];
#pragma unroll
    for (int nt = 0; nt < 2; ++nt) {
      const int n = (nt0 + nt) * 16 + l16;
      bf[nt] = *(const v8s*)(wpk + kc * 4096 + n * 32 + quad * 8);
    }
#pragma unroll
    for (int mt = 0; mt < 4; ++mt) {
      v8s af = *(const v8s*)(&a_s[mt * 16 + l16][kc * 32 + quad * 8]);
      acc[mt][0] = __builtin_amdgcn_mfma_f32_16x16x32_bf16(af, bf[0], acc[mt][0], 0, 0, 0);
      acc[mt][1] = __builtin_amdgcn_mfma_f32_16x16x32_bf16(af, bf[1], acc[mt][1], 0, 0, 0);
    }
  }

#pragma unroll
  for (int nt = 0; nt < 2; ++nt) {
    const int col = (nt0 + nt) * 16 + l16;
    const float bj = bias[col], sj = sc[col], tj = tc[col];
#pragma unroll
    for (int mt = 0; mt < 4; ++mt) {
#pragma unroll
      for (int r = 0; r < 4; ++r) {
        const int row = node0 + mt * 16 + quad * 4 + r;
        if (row < N) {
          float v = (acc[mt][nt][r] + bj) * sj + tj;
          out[(long)row * 128 + col] = fmaxf(v, 0.f);
        }
      }
    }
  }
}

extern "C" void kernel_launch(void* const* d_in, const int* in_sizes, int n_in,
                              void* d_out, int out_size, void* d_ws, size_t ws_size,
                              hipStream_t stream) {
  const float* x   = (const float*)d_in[0];
  const int*   ei  = (const int*)d_in[1];
  const float* W1l = (const float*)d_in[2];
  const float* b1  = (const float*)d_in[3];
  const float* W1r = (const float*)d_in[4];
  const float* g1  = (const float*)d_in[5];
  const float* be1 = (const float*)d_in[6];
  const float* rm1 = (const float*)d_in[7];
  const float* rv1 = (const float*)d_in[8];
  const float* W2l = (const float*)d_in[9];
  const float* b2  = (const float*)d_in[10];
  const float* W2r = (const float*)d_in[11];
  const float* g2  = (const float*)d_in[12];
  const float* be2 = (const float*)d_in[13];
  const float* rm2 = (const float*)d_in[14];
  const float* rv2 = (const float*)d_in[15];

  const int E = in_sizes[1] / 2;
  const int N = in_sizes[0] / 130;
  const int* src = ei;
  const int* dst = ei + E;

  // workspace carve (all 16B-aligned for N=200000)
  size_t aggN = (size_t)N * 130;
  float* agg = (float*)d_ws;           // N*130 floats (reused as N*128 for layer 2)
  float* deg = agg + aggN;             // N floats
  float* s1 = deg + N;
  float* t1 = s1 + 128;
  float* s2 = t1 + 128;
  float* t2 = s2 + 128;
  unsigned short* wpk1 = (unsigned short*)(t2 + 128);  // 9*4096 bf16
  unsigned short* wpk2 = wpk1 + 9 * 4096;              // 8*4096 bf16

  float* h1 = (float*)d_out;  // layer-1 output aliases d_out (safe: per-block row ownership)

  hipLaunchKernelGGL(bn_fold_k, dim3(1), dim3(128), 0, stream,
                     g1, be1, rm1, rv1, g2, be2, rm2, rv2, s1, t1, s2, t2);
  hipLaunchKernelGGL((pack_w_k<130, 9>), dim3(144), dim3(256), 0, stream, W1l, W1r, wpk1);
  hipLaunchKernelGGL((pack_w_k<128, 8>), dim3(128), dim3(256), 0, stream, W2l, W2r, wpk2);

  // zero agg(+deg) for layer 1
  int z1 = (int)((aggN + (size_t)N) / 4);
  hipLaunchKernelGGL(zero_f4, dim3((z1 + 255) / 256), dim3(256), 0, stream, (float4*)agg, z1);
  hipLaunchKernelGGL(deg_k, dim3((E + 255) / 256), dim3(256), 0, stream, dst, deg, E);
  hipLaunchKernelGGL((scatter_k<130>), dim3((E * 130 + 255) / 256), dim3(256), 0, stream,
                     x, src, dst, agg, E);
  hipLaunchKernelGGL((gemm_k<130, 9>), dim3((N + 63) / 64), dim3(256), 0, stream,
                     agg, deg, x, wpk1, b1, s1, t1, h1, N);

  // layer 2 (reuse agg buffer with F=128)
  int z2 = (int)(((size_t)N * 128) / 4);
  hipLaunchKernelGGL(zero_f4, dim3((z2 + 255) / 256), dim3(256), 0, stream, (float4*)agg, z2);
  hipLaunchKernelGGL((scatter_k<128>), dim3((E * 128 + 255) / 256), dim3(256), 0, stream,
                     h1, src, dst, agg, E);
  hipLaunchKernelGGL((gemm_k<128, 8>), dim3((N + 63) / 64), dim3(256), 0, stream,
                     agg, deg, h1, wpk2, b2, s2, t2, (float*)d_out, N);
}

// Round 2
// 670.587 us; speedup vs baseline: 1.5683x; 1.5683x over previous
//
#include <hip/hip_runtime.h>

typedef short v8s __attribute__((ext_vector_type(8)));
typedef float v4f __attribute__((ext_vector_type(4)));

__device__ __forceinline__ unsigned short f2bf(float x) {
  union { float f; unsigned int u; } c; c.f = x;
  unsigned int u = c.u;
  unsigned int r = (u + 0x7fffu + ((u >> 16) & 1u)) >> 16;
  return (unsigned short)r;
}

__global__ void bn_fold_k(const float* __restrict__ g1, const float* __restrict__ be1,
                          const float* __restrict__ rm1, const float* __restrict__ rv1,
                          const float* __restrict__ g2, const float* __restrict__ be2,
                          const float* __restrict__ rm2, const float* __restrict__ rv2,
                          float* __restrict__ s1, float* __restrict__ t1,
                          float* __restrict__ s2, float* __restrict__ t2) {
  int i = threadIdx.x;
  if (i < 128) {
    float sv = g1[i] * rsqrtf(rv1[i] + 1e-5f);
    s1[i] = sv; t1[i] = be1[i] - rm1[i] * sv;
    float sw = g2[i] * rsqrtf(rv2[i] + 1e-5f);
    s2[i] = sw; t2[i] = be2[i] - rm2[i] * sw;
  }
}

// Pack stacked [W_l; W_r] (K = 2F, zero-padded to KC*32) into B-fragment layout:
// wpk[kc*4096 + n*32 + kk], bf16. (layout verified by round-1 pass)
template<int F, int KC>
__global__ void pack_w_k(const float* __restrict__ Wl, const float* __restrict__ Wr,
                         unsigned short* __restrict__ wpk) {
  int i = blockIdx.x * 256 + threadIdx.x;
  if (i >= KC * 4096) return;
  int kk = i & 31, n = (i >> 5) & 127, kc = i >> 12;
  int k = kc * 32 + kk;
  float v = 0.f;
  if (k < F) v = Wl[k * 128 + n];
  else if (k < 2 * F) v = Wr[(k - F) * 128 + n];
  wpk[i] = f2bf(v);
}

// ---------- CSR build (once per call; graph shared by both layers) ----------

__global__ void zero_i_k(int* __restrict__ p, int n) {
  int i = blockIdx.x * 256 + threadIdx.x;
  if (i < n) p[i] = 0;
}

__global__ void count_k(const int* __restrict__ dst, int* __restrict__ degi, int E) {
  int i = blockIdx.x * 256 + threadIdx.x;
  if (i < E) atomicAdd(&degi[dst[i]], 1);
}

// per-1024-elem block exclusive scan; block totals to bsum
__global__ __launch_bounds__(256) void scan1_k(const int* __restrict__ degi,
                                               int* __restrict__ rowptr,
                                               int* __restrict__ bsum, int N) {
  __shared__ int sd[256];
  const int t = threadIdx.x;
  const int base = blockIdx.x * 1024 + t * 4;
  int v[4];
#pragma unroll
  for (int j = 0; j < 4; ++j) v[j] = (base + j < N) ? degi[base + j] : 0;
  const int tot = v[0] + v[1] + v[2] + v[3];
  sd[t] = tot;
  __syncthreads();
  for (int off = 1; off < 256; off <<= 1) {
    int o = (t >= off) ? sd[t - off] : 0;
    __syncthreads();
    sd[t] += o;
    __syncthreads();
  }
  int e = sd[t] - tot;  // exclusive prefix of this thread's 4-group
#pragma unroll
  for (int j = 0; j < 4; ++j) {
    if (base + j < N) rowptr[base + j] = e;
    e += v[j];
  }
  if (t == 255) bsum[blockIdx.x] = sd[255];
}

__global__ __launch_bounds__(256) void scan2_k(int* __restrict__ bsum, int nb) {
  __shared__ int sd[256];
  const int t = threadIdx.x;
  const int v = (t < nb) ? bsum[t] : 0;
  sd[t] = v;
  __syncthreads();
  for (int off = 1; off < 256; off <<= 1) {
    int o = (t >= off) ? sd[t - off] : 0;
    __syncthreads();
    sd[t] += o;
    __syncthreads();
  }
  if (t < nb) bsum[t] = sd[t] - v;  // exclusive, in place (single block)
}

__global__ void scan3_k(int* __restrict__ rowptr, int* __restrict__ cursor,
                        const int* __restrict__ bsum, int N, int E) {
  int i = blockIdx.x * 256 + threadIdx.x;
  if (i < N) {
    int v = rowptr[i] + bsum[i >> 10];
    rowptr[i] = v;
    cursor[i] = v;
  } else if (i == N) {
    rowptr[N] = E;
  }
}

__global__ void fill_k(const int* __restrict__ src, const int* __restrict__ dst,
                       int* __restrict__ cursor, int* __restrict__ nbr, int E) {
  int i = blockIdx.x * 256 + threadIdx.x;
  if (i < E) {
    int p = atomicAdd(&cursor[dst[i]], 1);
    nbr[p] = src[i];
  }
}

// ---------- fused gather-mean + GEMM + bias + BN + ReLU ----------
// out[n][j] = relu(((mean_{s in N(n)} x[s] | x[n]) . Wpk[:,j] + b[j]) * s[j] + t[j])
template<int F, int KC>
__global__ __launch_bounds__(256) void gemm_k(
    const float* __restrict__ xin, const int* __restrict__ rowptr,
    const int* __restrict__ nbr, const unsigned short* __restrict__ wpk,
    const float* __restrict__ bias, const float* __restrict__ sc,
    const float* __restrict__ tc, float* __restrict__ out, int N) {
  constexpr int KP = KC * 32;
  constexpr int LDA = KP + 8;
  constexpr int NI = (F + 63) / 64;
  __shared__ __align__(16) unsigned short a_s[64][LDA];
  const int tid = threadIdx.x;
  const int node0 = blockIdx.x * 64;
  const int wave = tid >> 6, lane = tid & 63;

  // staging: each wave owns 16 rows; gather-mean in fp32 regs, write bf16 [mean|x]
  for (int r = 0; r < 16; ++r) {
    const int row = wave * 16 + r;
    const int node = node0 + row;
    if (node < N) {
      const int r0 = rowptr[node], r1 = rowptr[node + 1];
      float acc[NI];
#pragma unroll
      for (int i = 0; i < NI; ++i) acc[i] = 0.f;
      for (int base = r0; base < r1; base += 64) {
        const int cnt = min(64, r1 - base);
        const int myn = (lane < cnt) ? nbr[base + lane] : 0;
        for (int e = 0; e < cnt; ++e) {
          const int s = __shfl(myn, e, 64);
          const float* xp = xin + (long)s * F;
#pragma unroll
          for (int i = 0; i < NI; ++i) {
            const int k = lane + 64 * i;
            if (k < F) acc[i] += xp[k];
          }
        }
      }
      const float inv = 1.0f / fmaxf((float)(r1 - r0), 1.0f);
      const float* xr = xin + (long)node * F;
#pragma unroll
      for (int i = 0; i < NI; ++i) {
        const int k = lane + 64 * i;
        if (k < F) {
          a_s[row][k]     = f2bf(acc[i] * inv);
          a_s[row][F + k] = f2bf(xr[k]);
        }
      }
      for (int k = 2 * F + lane; k < KP; k += 64) a_s[row][k] = 0;
    } else {
      for (int k = lane; k < KP; k += 64) a_s[row][k] = 0;
    }
  }
  __syncthreads();

  const int quad = lane >> 4, l16 = lane & 15;
  const int nt0 = wave * 2;
  v4f acc[4][2];
#pragma unroll
  for (int mt = 0; mt < 4; ++mt)
#pragma unroll
    for (int nt = 0; nt < 2; ++nt) acc[mt][nt] = (v4f){0.f, 0.f, 0.f, 0.f};

#pragma unroll
  for (int kc = 0; kc < KC; ++kc) {
    v8s bf[2];
#pragma unroll
    for (int nt = 0; nt < 2; ++nt) {
      const int n = (nt0 + nt) * 16 + l16;
      bf[nt] = *(const v8s*)(wpk + kc * 4096 + n * 32 + quad * 8);
    }
#pragma unroll
    for (int mt = 0; mt < 4; ++mt) {
      v8s af = *(const v8s*)(&a_s[mt * 16 + l16][kc * 32 + quad * 8]);
      acc[mt][0] = __builtin_amdgcn_mfma_f32_16x16x32_bf16(af, bf[0], acc[mt][0], 0, 0, 0);
      acc[mt][1] = __builtin_amdgcn_mfma_f32_16x16x32_bf16(af, bf[1], acc[mt][1], 0, 0, 0);
    }
  }

#pragma unroll
  for (int nt = 0; nt < 2; ++nt) {
    const int col = (nt0 + nt) * 16 + l16;
    const float bj = bias[col], sj = sc[col], tj = tc[col];
#pragma unroll
    for (int mt = 0; mt < 4; ++mt) {
#pragma unroll
      for (int r = 0; r < 4; ++r) {
        const int row = node0 + mt * 16 + quad * 4 + r;
        if (row < N) {
          float v = (acc[mt][nt][r] + bj) * sj + tj;
          out[(long)row * 128 + col] = fmaxf(v, 0.f);
        }
      }
    }
  }
}

extern "C" void kernel_launch(void* const* d_in, const int* in_sizes, int n_in,
                              void* d_out, int out_size, void* d_ws, size_t ws_size,
                              hipStream_t stream) {
  const float* x   = (const float*)d_in[0];
  const int*   ei  = (const int*)d_in[1];
  const float* W1l = (const float*)d_in[2];
  const float* b1  = (const float*)d_in[3];
  const float* W1r = (const float*)d_in[4];
  const float* g1  = (const float*)d_in[5];
  const float* be1 = (const float*)d_in[6];
  const float* rm1 = (const float*)d_in[7];
  const float* rv1 = (const float*)d_in[8];
  const float* W2l = (const float*)d_in[9];
  const float* b2  = (const float*)d_in[10];
  const float* W2r = (const float*)d_in[11];
  const float* g2  = (const float*)d_in[12];
  const float* be2 = (const float*)d_in[13];
  const float* rm2 = (const float*)d_in[14];
  const float* rv2 = (const float*)d_in[15];

  const int E = in_sizes[1] / 2;
  const int N = in_sizes[0] / 130;
  const int* src = ei;
  const int* dst = ei + E;

  // workspace carve (16B-aligned blocks first)
  float* h1 = (float*)d_ws;                                   // N*128 floats
  unsigned short* wpk1 = (unsigned short*)(h1 + (size_t)N * 128);  // 9*4096
  unsigned short* wpk2 = wpk1 + 9 * 4096;                     // 8*4096
  float* s1 = (float*)(wpk2 + 8 * 4096);
  float* t1 = s1 + 128;
  float* s2 = t1 + 128;
  float* t2 = s2 + 128;
  int* degi   = (int*)(t2 + 128);   // N ints (reused as cursor)
  int* rowptr = degi + N;           // N+1 ints
  int* bsum   = rowptr + N + 1;     // 256 ints
  int* nbr    = bsum + 256;         // E ints

  hipLaunchKernelGGL(bn_fold_k, dim3(1), dim3(128), 0, stream,
                     g1, be1, rm1, rv1, g2, be2, rm2, rv2, s1, t1, s2, t2);
  hipLaunchKernelGGL((pack_w_k<130, 9>), dim3(144), dim3(256), 0, stream, W1l, W1r, wpk1);
  hipLaunchKernelGGL((pack_w_k<128, 8>), dim3(128), dim3(256), 0, stream, W2l, W2r, wpk2);

  // CSR build (once; reused by both layers)
  hipLaunchKernelGGL(zero_i_k, dim3((N + 255) / 256), dim3(256), 0, stream, degi, N);
  hipLaunchKernelGGL(count_k, dim3((E + 255) / 256), dim3(256), 0, stream, dst, degi, E);
  const int nb = (N + 1023) / 1024;
  hipLaunchKernelGGL(scan1_k, dim3(nb), dim3(256), 0, stream, degi, rowptr, bsum, N);
  hipLaunchKernelGGL(scan2_k, dim3(1), dim3(256), 0, stream, bsum, nb);
  hipLaunchKernelGGL(scan3_k, dim3((N + 256) / 256), dim3(256), 0, stream,
                     rowptr, degi, bsum, N, E);
  hipLaunchKernelGGL(fill_k, dim3((E + 255) / 256), dim3(256), 0, stream,
                     src, dst, degi, nbr, E);

  // layer 1: gather-mean + GEMM fused
  hipLaunchKernelGGL((gemm_k<130, 9>), dim3((N + 63) / 64), dim3(256), 0, stream,
                     x, rowptr, nbr, wpk1, b1, s1, t1, h1, N);
  // layer 2
  hipLaunchKernelGGL((gemm_k<128, 8>), dim3((N + 63) / 64), dim3(256), 0, stream,
                     h1, rowptr, nbr, wpk2, b2, s2, t2, (float*)d_out, N);
}

// Round 3
// 560.541 us; speedup vs baseline: 1.8762x; 1.1963x over previous
//
#include <hip/hip_runtime.h>

typedef short v8s __attribute__((ext_vector_type(8)));
typedef float v4f __attribute__((ext_vector_type(4)));

__device__ __forceinline__ unsigned short f2bf(float x) {
  union { float f; unsigned int u; } c; c.f = x;
  unsigned int u = c.u;
  return (unsigned short)((u + 0x7fffu + ((u >> 16) & 1u)) >> 16);
}
__device__ __forceinline__ float bf2f(unsigned int hi16) {
  union { unsigned int u; float f; } c; c.u = hi16 << 16;
  return c.f;
}

__global__ void bn_fold_k(const float* __restrict__ g1, const float* __restrict__ be1,
                          const float* __restrict__ rm1, const float* __restrict__ rv1,
                          const float* __restrict__ g2, const float* __restrict__ be2,
                          const float* __restrict__ rm2, const float* __restrict__ rv2,
                          float* __restrict__ s1, float* __restrict__ t1,
                          float* __restrict__ s2, float* __restrict__ t2) {
  int i = threadIdx.x;
  if (i < 128) {
    float sv = g1[i] * rsqrtf(rv1[i] + 1e-5f);
    s1[i] = sv; t1[i] = be1[i] - rm1[i] * sv;
    float sw = g2[i] * rsqrtf(rv2[i] + 1e-5f);
    s2[i] = sw; t2[i] = be2[i] - rm2[i] * sw;
  }
}

// B-fragment pack: wpk[kc*4096 + n*32 + kk]; K layout: [Wl rows 0..F) at k<F,
// Wr rows at k in [XOFF, XOFF+F), zeros elsewhere. KP = KC*32.
template<int F, int XOFF, int KC>
__global__ void pack_w_k(const float* __restrict__ Wl, const float* __restrict__ Wr,
                         unsigned short* __restrict__ wpk) {
  int i = blockIdx.x * 256 + threadIdx.x;
  if (i >= KC * 4096) return;
  int kk = i & 31, n = (i >> 5) & 127, kc = i >> 12;
  int k = kc * 32 + kk;
  float v = 0.f;
  if (k < F) v = Wl[k * 128 + n];
  else if (k >= XOFF && k < XOFF + F) v = Wr[(k - XOFF) * 128 + n];
  wpk[i] = f2bf(v);
}

// ---------- CSR build ----------
__global__ void zero_i_k(int* __restrict__ p, int n) {
  int i = blockIdx.x * 256 + threadIdx.x;
  if (i < n) p[i] = 0;
}
__global__ void count_k(const int* __restrict__ dst, int* __restrict__ degi, int E) {
  int i = blockIdx.x * 256 + threadIdx.x;
  if (i < E) atomicAdd(&degi[dst[i]], 1);
}
__global__ __launch_bounds__(256) void scan1_k(const int* __restrict__ degi,
                                               int* __restrict__ rowptr,
                                               int* __restrict__ bsum, int N) {
  __shared__ int sd[256];
  const int t = threadIdx.x;
  const int base = blockIdx.x * 1024 + t * 4;
  int v[4];
#pragma unroll
  for (int j = 0; j < 4; ++j) v[j] = (base + j < N) ? degi[base + j] : 0;
  const int tot = v[0] + v[1] + v[2] + v[3];
  sd[t] = tot;
  __syncthreads();
  for (int off = 1; off < 256; off <<= 1) {
    int o = (t >= off) ? sd[t - off] : 0;
    __syncthreads();
    sd[t] += o;
    __syncthreads();
  }
  int e = sd[t] - tot;
#pragma unroll
  for (int j = 0; j < 4; ++j) {
    if (base + j < N) rowptr[base + j] = e;
    e += v[j];
  }
  if (t == 255) bsum[blockIdx.x] = sd[255];
}
__global__ __launch_bounds__(256) void scan2_k(int* __restrict__ bsum, int nb) {
  __shared__ int sd[256];
  const int t = threadIdx.x;
  const int v = (t < nb) ? bsum[t] : 0;
  sd[t] = v;
  __syncthreads();
  for (int off = 1; off < 256; off <<= 1) {
    int o = (t >= off) ? sd[t - off] : 0;
    __syncthreads();
    sd[t] += o;
    __syncthreads();
  }
  if (t < nb) bsum[t] = sd[t] - v;
}
__global__ void scan3_k(int* __restrict__ rowptr, int* __restrict__ cursor,
                        const int* __restrict__ bsum, int N, int E) {
  int i = blockIdx.x * 256 + threadIdx.x;
  if (i < N) {
    int v = rowptr[i] + bsum[i >> 10];
    rowptr[i] = v;
    cursor[i] = v;
  } else if (i == N) {
    rowptr[N] = E;
  }
}
__global__ void fill_k(const int* __restrict__ src, const int* __restrict__ dst,
                       int* __restrict__ cursor, int* __restrict__ nbr, int E) {
  int i = blockIdx.x * 256 + threadIdx.x;
  if (i < E) {
    int p = atomicAdd(&cursor[dst[i]], 1);
    nbr[p] = src[i];
  }
}

// ---------- gather-mean (one wave per node, lanes = feature pairs) ----------
// Layer 1: x fp32 (130/row) -> Mb bf16 rows (stride 136): [0:130)=mean, [130:136)=0
__global__ __launch_bounds__(256) void spmm1_k(const float* __restrict__ x,
                                               const int* __restrict__ rowptr,
                                               const int* __restrict__ nbr,
                                               unsigned short* __restrict__ Mb, int N) {
  const int gid = blockIdx.x * 4 + (threadIdx.x >> 6);
  const int lane = threadIdx.x & 63;
  if (gid >= N) return;
  const int r0 = rowptr[gid], r1 = rowptr[gid + 1];
  float2 a = make_float2(0.f, 0.f), b = make_float2(0.f, 0.f);
  for (int base = r0; base < r1; base += 64) {
    const int cnt = min(64, r1 - base);
    const int myn = (lane < cnt) ? nbr[base + lane] : 0;
    for (int e = 0; e < cnt; ++e) {
      const int s = __shfl(myn, e, 64);
      const float2* xp = (const float2*)(x + (long)s * 130);
      float2 v = xp[lane];
      a.x += v.x; a.y += v.y;
      if (lane == 0) { float2 w = xp[64]; b.x += w.x; b.y += w.y; }
    }
  }
  const float inv = 1.0f / fmaxf((float)(r1 - r0), 1.0f);
  unsigned short* mrow = Mb + (long)gid * 136;
  ushort2 p; p.x = f2bf(a.x * inv); p.y = f2bf(a.y * inv);
  *(ushort2*)(mrow + 2 * lane) = p;
  if (lane == 0) { ushort2 q; q.x = f2bf(b.x * inv); q.y = f2bf(b.y * inv);
                   *(ushort2*)(mrow + 128) = q; }
  if (lane >= 1 && lane < 4) { ushort2 z; z.x = 0; z.y = 0;
                               *(ushort2*)(mrow + 128 + 2 * lane) = z; }
}

// Layer 2: h1 bf16 (128/row) -> Mb rows [0:128)=mean2
__global__ __launch_bounds__(256) void spmm2_k(const unsigned short* __restrict__ h1,
                                               const int* __restrict__ rowptr,
                                               const int* __restrict__ nbr,
                                               unsigned short* __restrict__ Mb, int N) {
  const int gid = blockIdx.x * 4 + (threadIdx.x >> 6);
  const int lane = threadIdx.x & 63;
  if (gid >= N) return;
  const int r0 = rowptr[gid], r1 = rowptr[gid + 1];
  float2 a = make_float2(0.f, 0.f);
  for (int base = r0; base < r1; base += 64) {
    const int cnt = min(64, r1 - base);
    const int myn = (lane < cnt) ? nbr[base + lane] : 0;
    for (int e = 0; e < cnt; ++e) {
      const int s = __shfl(myn, e, 64);
      const unsigned int d = *(const unsigned int*)(h1 + (long)s * 128 + 2 * lane);
      a.x += bf2f(d & 0xffffu);
      a.y += bf2f(d >> 16);
    }
  }
  const float inv = 1.0f / fmaxf((float)(r1 - r0), 1.0f);
  ushort2 p; p.x = f2bf(a.x * inv); p.y = f2bf(a.y * inv);
  *(ushort2*)(Mb + (long)gid * 136 + 2 * lane) = p;
}

// ---------- GEMM + bias + BN + ReLU (streaming staging) ----------
// L2MODE=false: K=[mean(130)|pad6|x fp32->bf16(130)|pad22], KP=288, out=h1 bf16
// L2MODE=true : K=[mean2(128)|h1(128)], KP=256, out=d_out fp32
template<int KC, int LDA, bool L2MODE>
__global__ __launch_bounds__(256) void gemm_k(
    const unsigned short* __restrict__ Mb, const void* __restrict__ xroot,
    const unsigned short* __restrict__ wpk, const float* __restrict__ bias,
    const float* __restrict__ sc, const float* __restrict__ tc,
    void* __restrict__ out, int N) {
  __shared__ __align__(16) unsigned short a_s[64][LDA];
  const int tid = threadIdx.x;
  const int node0 = blockIdx.x * 64;

  // mean part: 16B chunks from Mb (stride 136)
  constexpr int MCH = L2MODE ? 16 : 17;
  for (int idx = tid; idx < 64 * MCH; idx += 256) {
    const int row = idx / MCH, c = idx - row * MCH;
    const int node = node0 + row;
    v8s v = {0, 0, 0, 0, 0, 0, 0, 0};
    if (node < N) v = *(const v8s*)(Mb + (long)node * 136 + c * 8);
    *(v8s*)&a_s[row][c * 8] = v;
  }
  if (!L2MODE) {
    const float* xf = (const float*)xroot;
    for (int idx = tid; idx < 64 * 65; idx += 256) {  // 65 float2 per row
      const int row = idx / 65, c = idx - row * 65;
      const int node = node0 + row;
      float2 v = make_float2(0.f, 0.f);
      if (node < N) v = *(const float2*)(xf + (long)node * 130 + 2 * c);
      ushort2 p; p.x = f2bf(v.x); p.y = f2bf(v.y);
      *(ushort2*)&a_s[row][136 + 2 * c] = p;
    }
    for (int idx = tid; idx < 64 * 11; idx += 256) {  // zeros [266:288)
      const int row = idx / 11, c = idx - row * 11;
      *(unsigned int*)&a_s[row][266 + 2 * c] = 0u;
    }
  } else {
    const unsigned short* hb = (const unsigned short*)xroot;
    for (int idx = tid; idx < 64 * 16; idx += 256) {
      const int row = idx >> 4, c = idx & 15;
      const int node = node0 + row;
      v8s v = {0, 0, 0, 0, 0, 0, 0, 0};
      if (node < N) v = *(const v8s*)(hb + (long)node * 128 + c * 8);
      *(v8s*)&a_s[row][128 + c * 8] = v;
    }
  }
  __syncthreads();

  const int wave = tid >> 6, lane = tid & 63;
  const int quad = lane >> 4, l16 = lane & 15;
  const int nt0 = wave * 2;
  v4f acc[4][2];
#pragma unroll
  for (int mt = 0; mt < 4; ++mt)
#pragma unroll
    for (int nt = 0; nt < 2; ++nt) acc[mt][nt] = (v4f){0.f, 0.f, 0.f, 0.f};

#pragma unroll
  for (int kc = 0; kc < KC; ++kc) {
    v8s bf[2];
#pragma unroll
    for (int nt = 0; nt < 2; ++nt) {
      const int n = (nt0 + nt) * 16 + l16;
      bf[nt] = *(const v8s*)(wpk + kc * 4096 + n * 32 + quad * 8);
    }
#pragma unroll
    for (int mt = 0; mt < 4; ++mt) {
      v8s af = *(const v8s*)(&a_s[mt * 16 + l16][kc * 32 + quad * 8]);
      acc[mt][0] = __builtin_amdgcn_mfma_f32_16x16x32_bf16(af, bf[0], acc[mt][0], 0, 0, 0);
      acc[mt][1] = __builtin_amdgcn_mfma_f32_16x16x32_bf16(af, bf[1], acc[mt][1], 0, 0, 0);
    }
  }

#pragma unroll
  for (int nt = 0; nt < 2; ++nt) {
    const int col = (nt0 + nt) * 16 + l16;
    const float bj = bias[col], sj = sc[col], tj = tc[col];
#pragma unroll
    for (int mt = 0; mt < 4; ++mt) {
#pragma unroll
      for (int r = 0; r < 4; ++r) {
        const int row = node0 + mt * 16 + quad * 4 + r;
        if (row < N) {
          float v = fmaxf((acc[mt][nt][r] + bj) * sj + tj, 0.f);
          if (L2MODE) ((float*)out)[(long)row * 128 + col] = v;
          else ((unsigned short*)out)[(long)row * 128 + col] = f2bf(v);
        }
      }
    }
  }
}

extern "C" void kernel_launch(void* const* d_in, const int* in_sizes, int n_in,
                              void* d_out, int out_size, void* d_ws, size_t ws_size,
                              hipStream_t stream) {
  const float* x   = (const float*)d_in[0];
  const int*   ei  = (const int*)d_in[1];
  const float* W1l = (const float*)d_in[2];
  const float* b1  = (const float*)d_in[3];
  const float* W1r = (const float*)d_in[4];
  const float* g1  = (const float*)d_in[5];
  const float* be1 = (const float*)d_in[6];
  const float* rm1 = (const float*)d_in[7];
  const float* rv1 = (const float*)d_in[8];
  const float* W2l = (const float*)d_in[9];
  const float* b2  = (const float*)d_in[10];
  const float* W2r = (const float*)d_in[11];
  const float* g2  = (const float*)d_in[12];
  const float* be2 = (const float*)d_in[13];
  const float* rm2 = (const float*)d_in[14];
  const float* rv2 = (const float*)d_in[15];

  const int E = in_sizes[1] / 2;
  const int N = in_sizes[0] / 130;
  const int* src = ei;
  const int* dst = ei + E;

  // workspace carve
  unsigned short* Mb  = (unsigned short*)d_ws;        // N*136 bf16 (mean, both layers)
  unsigned short* h1  = Mb + (size_t)N * 136;         // N*128 bf16
  unsigned short* wpk1 = h1 + (size_t)N * 128;        // 9*4096
  unsigned short* wpk2 = wpk1 + 9 * 4096;             // 8*4096
  float* s1 = (float*)(wpk2 + 8 * 4096);
  float* t1 = s1 + 128;
  float* s2 = t1 + 128;
  float* t2 = s2 + 128;
  int* degi   = (int*)(t2 + 128);   // N (reused as cursor)
  int* rowptr = degi + N;           // N+1
  int* bsum   = rowptr + N + 1;     // 256
  int* nbr    = bsum + 256;         // E

  hipLaunchKernelGGL(bn_fold_k, dim3(1), dim3(128), 0, stream,
                     g1, be1, rm1, rv1, g2, be2, rm2, rv2, s1, t1, s2, t2);
  hipLaunchKernelGGL((pack_w_k<130, 136, 9>), dim3(144), dim3(256), 0, stream, W1l, W1r, wpk1);
  hipLaunchKernelGGL((pack_w_k<128, 128, 8>), dim3(128), dim3(256), 0, stream, W2l, W2r, wpk2);

  // CSR build
  hipLaunchKernelGGL(zero_i_k, dim3((N + 255) / 256), dim3(256), 0, stream, degi, N);
  hipLaunchKernelGGL(count_k, dim3((E + 255) / 256), dim3(256), 0, stream, dst, degi, E);
  const int nb = (N + 1023) / 1024;
  hipLaunchKernelGGL(scan1_k, dim3(nb), dim3(256), 0, stream, degi, rowptr, bsum, N);
  hipLaunchKernelGGL(scan2_k, dim3(1), dim3(256), 0, stream, bsum, nb);
  hipLaunchKernelGGL(scan3_k, dim3((N + 256) / 256), dim3(256), 0, stream,
                     rowptr, degi, bsum, N, E);
  hipLaunchKernelGGL(fill_k, dim3((E + 255) / 256), dim3(256), 0, stream,
                     src, dst, degi, nbr, E);

  const int nsb = (N + 3) / 4;   // spmm: one wave per node, 4 waves/block
  const int ngb = (N + 63) / 64; // gemm: 64 rows per block

  // layer 1
  hipLaunchKernelGGL(spmm1_k, dim3(nsb), dim3(256), 0, stream, x, rowptr, nbr, Mb, N);
  hipLaunchKernelGGL((gemm_k<9, 296, false>), dim3(ngb), dim3(256), 0, stream,
                     Mb, (const void*)x, wpk1, b1, s1, t1, (void*)h1, N);
  // layer 2
  hipLaunchKernelGGL(spmm2_k, dim3(nsb), dim3(256), 0, stream, h1, rowptr, nbr, Mb, N);
  hipLaunchKernelGGL((gemm_k<8, 264, true>), dim3(ngb), dim3(256), 0, stream,
                     Mb, (const void*)h1, wpk2, b2, s2, t2, d_out, N);
}

// Round 4
// 525.980 us; speedup vs baseline: 1.9994x; 1.0657x over previous
//
#include <hip/hip_runtime.h>

typedef short v8s __attribute__((ext_vector_type(8)));
typedef float v4f __attribute__((ext_vector_type(4)));

__device__ __forceinline__ unsigned short f2bf(float x) {
  union { float f; unsigned int u; } c; c.f = x;
  unsigned int u = c.u;
  return (unsigned short)((u + 0x7fffu + ((u >> 16) & 1u)) >> 16);
}
__device__ __forceinline__ float bf2f(unsigned int hi16) {
  union { unsigned int u; float f; } c; c.u = hi16 << 16;
  return c.f;
}
__device__ __forceinline__ ushort2 pk(float2 v) {
  ushort2 p; p.x = f2bf(v.x); p.y = f2bf(v.y); return p;
}

__global__ void bn_fold_k(const float* __restrict__ g1, const float* __restrict__ be1,
                          const float* __restrict__ rm1, const float* __restrict__ rv1,
                          const float* __restrict__ g2, const float* __restrict__ be2,
                          const float* __restrict__ rm2, const float* __restrict__ rv2,
                          float* __restrict__ s1, float* __restrict__ t1,
                          float* __restrict__ s2, float* __restrict__ t2) {
  int i = threadIdx.x;
  if (i < 128) {
    float sv = g1[i] * rsqrtf(rv1[i] + 1e-5f);
    s1[i] = sv; t1[i] = be1[i] - rm1[i] * sv;
    float sw = g2[i] * rsqrtf(rv2[i] + 1e-5f);
    s2[i] = sw; t2[i] = be2[i] - rm2[i] * sw;
  }
}

// B-fragment pack: wpk[kc*4096 + n*32 + kk]; Wl rows at k<F, Wr rows at [XOFF,XOFF+F)
template<int F, int XOFF, int KC>
__global__ void pack_w_k(const float* __restrict__ Wl, const float* __restrict__ Wr,
                         unsigned short* __restrict__ wpk) {
  int i = blockIdx.x * 256 + threadIdx.x;
  if (i >= KC * 4096) return;
  int kk = i & 31, n = (i >> 5) & 127, kc = i >> 12;
  int k = kc * 32 + kk;
  float v = 0.f;
  if (k < F) v = Wl[k * 128 + n];
  else if (k >= XOFF && k < XOFF + F) v = Wr[(k - XOFF) * 128 + n];
  wpk[i] = f2bf(v);
}

// ---------- CSR build ----------
__global__ void zero_i_k(int* __restrict__ p, int n) {
  int i = blockIdx.x * 256 + threadIdx.x;
  if (i < n) p[i] = 0;
}
__global__ void count_k(const int* __restrict__ dst, int* __restrict__ degi, int E) {
  int i = blockIdx.x * 256 + threadIdx.x;
  if (i < E) atomicAdd(&degi[dst[i]], 1);
}
__global__ __launch_bounds__(256) void scan1_k(const int* __restrict__ degi,
                                               int* __restrict__ rowptr,
                                               int* __restrict__ bsum, int N) {
  __shared__ int sd[256];
  const int t = threadIdx.x;
  const int base = blockIdx.x * 1024 + t * 4;
  int v[4];
#pragma unroll
  for (int j = 0; j < 4; ++j) v[j] = (base + j < N) ? degi[base + j] : 0;
  const int tot = v[0] + v[1] + v[2] + v[3];
  sd[t] = tot;
  __syncthreads();
  for (int off = 1; off < 256; off <<= 1) {
    int o = (t >= off) ? sd[t - off] : 0;
    __syncthreads();
    sd[t] += o;
    __syncthreads();
  }
  int e = sd[t] - tot;
#pragma unroll
  for (int j = 0; j < 4; ++j) {
    if (base + j < N) rowptr[base + j] = e;
    e += v[j];
  }
  if (t == 255) bsum[blockIdx.x] = sd[255];
}
__global__ __launch_bounds__(256) void scan2_k(int* __restrict__ bsum, int nb) {
  __shared__ int sd[256];
  const int t = threadIdx.x;
  const int v = (t < nb) ? bsum[t] : 0;
  sd[t] = v;
  __syncthreads();
  for (int off = 1; off < 256; off <<= 1) {
    int o = (t >= off) ? sd[t - off] : 0;
    __syncthreads();
    sd[t] += o;
    __syncthreads();
  }
  if (t < nb) bsum[t] = sd[t] - v;
}
__global__ void scan3_k(int* __restrict__ rowptr, int* __restrict__ cursor,
                        const int* __restrict__ bsum, int N, int E) {
  int i = blockIdx.x * 256 + threadIdx.x;
  if (i < N) {
    int v = rowptr[i] + bsum[i >> 10];
    rowptr[i] = v;
    cursor[i] = v;
  } else if (i == N) {
    rowptr[N] = E;
  }
}
__global__ void fill_k(const int* __restrict__ src, const int* __restrict__ dst,
                       int* __restrict__ cursor, int* __restrict__ nbr, int E) {
  int i = blockIdx.x * 256 + threadIdx.x;
  if (i < E) {
    int p = atomicAdd(&cursor[dst[i]], 1);
    nbr[p] = src[i];
  }
}

// ---------- layer-1 gather-mean + root pack ----------
// A row (stride 288 bf16): [0:130)=mean, [130:136)=0, [136:266)=x(root), [266:288)=0
__global__ __launch_bounds__(256) void spmm1_k(const float* __restrict__ x,
                                               const int* __restrict__ rowptr,
                                               const int* __restrict__ nbr,
                                               unsigned short* __restrict__ A, int N) {
  const int gid = blockIdx.x * 4 + (threadIdx.x >> 6);
  const int lane = threadIdx.x & 63;
  if (gid >= N) return;
  const int r0 = rowptr[gid], r1 = rowptr[gid + 1];
  const int d = r1 - r0;
  // root row (independent of gather chain; issued early)
  const float2* xr = (const float2*)(x + (long)gid * 130);
  const float2 rv = xr[lane];
  const float2 rw = (lane == 0) ? xr[64] : make_float2(0.f, 0.f);

  float2 a = make_float2(0.f, 0.f), b = make_float2(0.f, 0.f);
  if (d <= 64) {
    const int myn = (lane < d) ? nbr[r0 + lane] : 0;
    int e = 0;
    for (; e + 4 <= d; e += 4) {
      const int s0 = __shfl(myn, e, 64), s1 = __shfl(myn, e + 1, 64);
      const int s2 = __shfl(myn, e + 2, 64), s3 = __shfl(myn, e + 3, 64);
      const float2* p0 = (const float2*)(x + (long)s0 * 130);
      const float2* p1 = (const float2*)(x + (long)s1 * 130);
      const float2* p2 = (const float2*)(x + (long)s2 * 130);
      const float2* p3 = (const float2*)(x + (long)s3 * 130);
      float2 v0 = p0[lane], v1 = p1[lane], v2 = p2[lane], v3 = p3[lane];
      float2 w0 = make_float2(0.f, 0.f), w1 = w0, w2 = w0, w3 = w0;
      if (lane == 0) { w0 = p0[64]; w1 = p1[64]; w2 = p2[64]; w3 = p3[64]; }
      a.x += v0.x + v1.x + v2.x + v3.x; a.y += v0.y + v1.y + v2.y + v3.y;
      b.x += w0.x + w1.x + w2.x + w3.x; b.y += w0.y + w1.y + w2.y + w3.y;
    }
    float2 v0 = make_float2(0.f, 0.f), v1 = v0, v2 = v0;
    float2 w0 = v0, w1 = v0, w2 = v0;
    if (e < d) {
      const float2* p = (const float2*)(x + (long)__shfl(myn, e, 64) * 130);
      v0 = p[lane]; if (lane == 0) w0 = p[64];
    }
    if (e + 1 < d) {
      const float2* p = (const float2*)(x + (long)__shfl(myn, e + 1, 64) * 130);
      v1 = p[lane]; if (lane == 0) w1 = p[64];
    }
    if (e + 2 < d) {
      const float2* p = (const float2*)(x + (long)__shfl(myn, e + 2, 64) * 130);
      v2 = p[lane]; if (lane == 0) w2 = p[64];
    }
    a.x += v0.x + v1.x + v2.x; a.y += v0.y + v1.y + v2.y;
    b.x += w0.x + w1.x + w2.x; b.y += w0.y + w1.y + w2.y;
  } else {
    for (int base = r0; base < r1; base += 64) {
      const int cnt = min(64, r1 - base);
      const int myn = (lane < cnt) ? nbr[base + lane] : 0;
      for (int e = 0; e < cnt; ++e) {
        const float2* p = (const float2*)(x + (long)__shfl(myn, e, 64) * 130);
        float2 v = p[lane];
        a.x += v.x; a.y += v.y;
        if (lane == 0) { float2 w = p[64]; b.x += w.x; b.y += w.y; }
      }
    }
  }
  const float inv = 1.0f / fmaxf((float)d, 1.0f);
  unsigned short* Ar = A + (long)gid * 288;
  a.x *= inv; a.y *= inv;
  *(ushort2*)(Ar + 2 * lane) = pk(a);                    // mean pairs 0..63
  *(ushort2*)(Ar + 136 + 2 * lane) = pk(rv);             // x pairs 0..63
  if (lane == 0) {
    b.x *= inv; b.y *= inv;
    *(ushort2*)(Ar + 128) = pk(b);                       // mean elems 128,129
    *(ushort2*)(Ar + 264) = pk(rw);                      // x elems 128,129
  }
  if (lane >= 1 && lane < 4) *(unsigned int*)(Ar + 130 + 2 * (lane - 1)) = 0u;
  if (lane >= 4 && lane < 15) *(unsigned int*)(Ar + 266 + 2 * (lane - 4)) = 0u;
}

// ---------- layer-2 gather-mean (h1 bf16 lives at A[row*288+128..256)) ----------
__global__ __launch_bounds__(256) void spmm2_k(const int* __restrict__ rowptr,
                                               const int* __restrict__ nbr,
                                               unsigned short* __restrict__ A, int N) {
  const int gid = blockIdx.x * 4 + (threadIdx.x >> 6);
  const int lane = threadIdx.x & 63;
  if (gid >= N) return;
  const int r0 = rowptr[gid], r1 = rowptr[gid + 1];
  const int d = r1 - r0;
  float2 a = make_float2(0.f, 0.f);
  if (d <= 64) {
    const int myn = (lane < d) ? nbr[r0 + lane] : 0;
    int e = 0;
    for (; e + 4 <= d; e += 4) {
      const int s0 = __shfl(myn, e, 64), s1 = __shfl(myn, e + 1, 64);
      const int s2 = __shfl(myn, e + 2, 64), s3 = __shfl(myn, e + 3, 64);
      const unsigned int u0 = *(const unsigned int*)(A + (long)s0 * 288 + 128 + 2 * lane);
      const unsigned int u1 = *(const unsigned int*)(A + (long)s1 * 288 + 128 + 2 * lane);
      const unsigned int u2 = *(const unsigned int*)(A + (long)s2 * 288 + 128 + 2 * lane);
      const unsigned int u3 = *(const unsigned int*)(A + (long)s3 * 288 + 128 + 2 * lane);
      a.x += bf2f(u0 & 0xffffu) + bf2f(u1 & 0xffffu) + bf2f(u2 & 0xffffu) + bf2f(u3 & 0xffffu);
      a.y += bf2f(u0 >> 16) + bf2f(u1 >> 16) + bf2f(u2 >> 16) + bf2f(u3 >> 16);
    }
    unsigned int u0 = 0, u1 = 0, u2 = 0;
    if (e < d)     u0 = *(const unsigned int*)(A + (long)__shfl(myn, e, 64) * 288 + 128 + 2 * lane);
    if (e + 1 < d) u1 = *(const unsigned int*)(A + (long)__shfl(myn, e + 1, 64) * 288 + 128 + 2 * lane);
    if (e + 2 < d) u2 = *(const unsigned int*)(A + (long)__shfl(myn, e + 2, 64) * 288 + 128 + 2 * lane);
    a.x += bf2f(u0 & 0xffffu) + bf2f(u1 & 0xffffu) + bf2f(u2 & 0xffffu);
    a.y += bf2f(u0 >> 16) + bf2f(u1 >> 16) + bf2f(u2 >> 16);
  } else {
    for (int base = r0; base < r1; base += 64) {
      const int cnt = min(64, r1 - base);
      const int myn = (lane < cnt) ? nbr[base + lane] : 0;
      for (int e = 0; e < cnt; ++e) {
        const unsigned int u = *(const unsigned int*)(A + (long)__shfl(myn, e, 64) * 288 + 128 + 2 * lane);
        a.x += bf2f(u & 0xffffu);
        a.y += bf2f(u >> 16);
      }
    }
  }
  const float inv = 1.0f / fmaxf((float)d, 1.0f);
  a.x *= inv; a.y *= inv;
  *(ushort2*)(A + (long)gid * 288 + 2 * lane) = pk(a);   // mean2 at [0:128)
}

// ---------- GEMM + bias + BN + ReLU ----------
// Stages KC*32 bf16 per row straight from A (stride 288). L2MODE picks output.
template<int KC, bool L2MODE>
__global__ __launch_bounds__(256) void gemm_k(
    const unsigned short* __restrict__ A, const unsigned short* __restrict__ wpk,
    const float* __restrict__ bias, const float* __restrict__ sc,
    const float* __restrict__ tc, void* __restrict__ out, int N) {
  constexpr int KP = KC * 32;
  constexpr int LDA = KP + 8;
  __shared__ __align__(16) unsigned short a_s[64][LDA];
  const int tid = threadIdx.x;
  const int node0 = blockIdx.x * 64;

  {
    const int row = tid >> 2, t4 = tid & 3;
    const int node = node0 + row;
    const unsigned short* Ar = A + (long)node * 288;
#pragma unroll
    for (int i = 0; i < KC; ++i) {
      const int c = t4 + 4 * i;   // 16B chunk index, c < KC*4
      v8s v = {0, 0, 0, 0, 0, 0, 0, 0};
      if (node < N) v = *(const v8s*)(Ar + c * 8);
      *(v8s*)&a_s[row][c * 8] = v;
    }
  }
  __syncthreads();

  const int wave = tid >> 6, lane = tid & 63;
  const int quad = lane >> 4, l16 = lane & 15;
  const int nt0 = wave * 2;
  v4f acc[4][2];
#pragma unroll
  for (int mt = 0; mt < 4; ++mt)
#pragma unroll
    for (int nt = 0; nt < 2; ++nt) acc[mt][nt] = (v4f){0.f, 0.f, 0.f, 0.f};

#pragma unroll
  for (int kc = 0; kc < KC; ++kc) {
    v8s bf[2];
#pragma unroll
    for (int nt = 0; nt < 2; ++nt) {
      const int n = (nt0 + nt) * 16 + l16;
      bf[nt] = *(const v8s*)(wpk + kc * 4096 + n * 32 + quad * 8);
    }
#pragma unroll
    for (int mt = 0; mt < 4; ++mt) {
      v8s af = *(const v8s*)(&a_s[mt * 16 + l16][kc * 32 + quad * 8]);
      acc[mt][0] = __builtin_amdgcn_mfma_f32_16x16x32_bf16(af, bf[0], acc[mt][0], 0, 0, 0);
      acc[mt][1] = __builtin_amdgcn_mfma_f32_16x16x32_bf16(af, bf[1], acc[mt][1], 0, 0, 0);
    }
  }

#pragma unroll
  for (int nt = 0; nt < 2; ++nt) {
    const int col = (nt0 + nt) * 16 + l16;
    const float bj = bias[col], sj = sc[col], tj = tc[col];
#pragma unroll
    for (int mt = 0; mt < 4; ++mt) {
#pragma unroll
      for (int r = 0; r < 4; ++r) {
        const int row = node0 + mt * 16 + quad * 4 + r;
        if (row < N) {
          float v = fmaxf((acc[mt][nt][r] + bj) * sj + tj, 0.f);
          if (L2MODE) ((float*)out)[(long)row * 128 + col] = v;
          else ((unsigned short*)out)[(long)row * 288 + 128 + col] = f2bf(v);
        }
      }
    }
  }
}

extern "C" void kernel_launch(void* const* d_in, const int* in_sizes, int n_in,
                              void* d_out, int out_size, void* d_ws, size_t ws_size,
                              hipStream_t stream) {
  const float* x   = (const float*)d_in[0];
  const int*   ei  = (const int*)d_in[1];
  const float* W1l = (const float*)d_in[2];
  const float* b1  = (const float*)d_in[3];
  const float* W1r = (const float*)d_in[4];
  const float* g1  = (const float*)d_in[5];
  const float* be1 = (const float*)d_in[6];
  const float* rm1 = (const float*)d_in[7];
  const float* rv1 = (const float*)d_in[8];
  const float* W2l = (const float*)d_in[9];
  const float* b2  = (const float*)d_in[10];
  const float* W2r = (const float*)d_in[11];
  const float* g2  = (const float*)d_in[12];
  const float* be2 = (const float*)d_in[13];
  const float* rm2 = (const float*)d_in[14];
  const float* rv2 = (const float*)d_in[15];

  const int E = in_sizes[1] / 2;
  const int N = in_sizes[0] / 130;
  const int* src = ei;
  const int* dst = ei + E;

  // workspace carve
  unsigned short* A    = (unsigned short*)d_ws;   // N*288 bf16 (A rows, both layers)
  unsigned short* wpk1 = A + (size_t)N * 288;     // 9*4096
  unsigned short* wpk2 = wpk1 + 9 * 4096;         // 8*4096
  float* s1 = (float*)(wpk2 + 8 * 4096);
  float* t1 = s1 + 128;
  float* s2 = t1 + 128;
  float* t2 = s2 + 128;
  int* degi   = (int*)(t2 + 128);   // N (reused as cursor)
  int* rowptr = degi + N;           // N+1
  int* bsum   = rowptr + N + 1;     // 256
  int* nbr    = bsum + 256;         // E

  hipLaunchKernelGGL(bn_fold_k, dim3(1), dim3(128), 0, stream,
                     g1, be1, rm1, rv1, g2, be2, rm2, rv2, s1, t1, s2, t2);
  hipLaunchKernelGGL((pack_w_k<130, 136, 9>), dim3(144), dim3(256), 0, stream, W1l, W1r, wpk1);
  hipLaunchKernelGGL((pack_w_k<128, 128, 8>), dim3(128), dim3(256), 0, stream, W2l, W2r, wpk2);

  // CSR build
  hipLaunchKernelGGL(zero_i_k, dim3((N + 255) / 256), dim3(256), 0, stream, degi, N);
  hipLaunchKernelGGL(count_k, dim3((E + 255) / 256), dim3(256), 0, stream, dst, degi, E);
  const int nb = (N + 1023) / 1024;
  hipLaunchKernelGGL(scan1_k, dim3(nb), dim3(256), 0, stream, degi, rowptr, bsum, N);
  hipLaunchKernelGGL(scan2_k, dim3(1), dim3(256), 0, stream, bsum, nb);
  hipLaunchKernelGGL(scan3_k, dim3((N + 256) / 256), dim3(256), 0, stream,
                     rowptr, degi, bsum, N, E);
  hipLaunchKernelGGL(fill_k, dim3((E + 255) / 256), dim3(256), 0, stream,
                     src, dst, degi, nbr, E);

  const int nsb = (N + 3) / 4;
  const int ngb = (N + 63) / 64;

  // layer 1
  hipLaunchKernelGGL(spmm1_k, dim3(nsb), dim3(256), 0, stream, x, rowptr, nbr, A, N);
  hipLaunchKernelGGL((gemm_k<9, false>), dim3(ngb), dim3(256), 0, stream,
                     A, wpk1, b1, s1, t1, (void*)A, N);
  // layer 2
  hipLaunchKernelGGL(spmm2_k, dim3(nsb), dim3(256), 0, stream, rowptr, nbr, A, N);
  hipLaunchKernelGGL((gemm_k<8, true>), dim3(ngb), dim3(256), 0, stream,
                     A, wpk2, b2, s2, t2, d_out, N);
}

// Round 5
// 513.891 us; speedup vs baseline: 2.0465x; 1.0235x over previous
//
#include <hip/hip_runtime.h>

typedef short v8s __attribute__((ext_vector_type(8)));
typedef float v4f __attribute__((ext_vector_type(4)));

__device__ __forceinline__ unsigned short f2bf(float x) {
  union { float f; unsigned int u; } c; c.f = x;
  unsigned int u = c.u;
  return (unsigned short)((u + 0x7fffu + ((u >> 16) & 1u)) >> 16);
}
__device__ __forceinline__ float bf2f(unsigned int hi16) {
  union { unsigned int u; float f; } c; c.u = hi16 << 16;
  return c.f;
}
__device__ __forceinline__ ushort2 pk(float2 v) {
  ushort2 p; p.x = f2bf(v.x); p.y = f2bf(v.y); return p;
}

// A row stride (shorts): [0:136)=mean slot, [136:264)=h1 slot, [264:272) spare
#define ASTR 272
// xb row stride (shorts): [0:130)=x bf16, [130:136)=0
#define XSTR 136

__global__ void bn_fold_k(const float* __restrict__ g1, const float* __restrict__ be1,
                          const float* __restrict__ rm1, const float* __restrict__ rv1,
                          const float* __restrict__ g2, const float* __restrict__ be2,
                          const float* __restrict__ rm2, const float* __restrict__ rv2,
                          float* __restrict__ s1, float* __restrict__ t1,
                          float* __restrict__ s2, float* __restrict__ t2) {
  int i = threadIdx.x;
  if (i < 128) {
    float sv = g1[i] * rsqrtf(rv1[i] + 1e-5f);
    s1[i] = sv; t1[i] = be1[i] - rm1[i] * sv;
    float sw = g2[i] * rsqrtf(rv2[i] + 1e-5f);
    s2[i] = sw; t2[i] = be2[i] - rm2[i] * sw;
  }
}

// B-fragment pack: wpk[kc*4096 + n*32 + kk]; Wl rows at k<F, Wr rows at [XOFF,XOFF+F)
template<int F, int XOFF, int KC>
__global__ void pack_w_k(const float* __restrict__ Wl, const float* __restrict__ Wr,
                         unsigned short* __restrict__ wpk) {
  int i = blockIdx.x * 256 + threadIdx.x;
  if (i >= KC * 4096) return;
  int kk = i & 31, n = (i >> 5) & 127, kc = i >> 12;
  int k = kc * 32 + kk;
  float v = 0.f;
  if (k < F) v = Wl[k * 128 + n];
  else if (k >= XOFF && k < XOFF + F) v = Wr[(k - XOFF) * 128 + n];
  wpk[i] = f2bf(v);
}

// x fp32 -> xb bf16 (row stride 136, zeros pad); row N = sentinel zeros.
// Also zeroes A row N's h1 slot (sentinel for spmm2).
__global__ __launch_bounds__(256) void xb_k(const float* __restrict__ x,
                                            unsigned short* __restrict__ xb,
                                            unsigned short* __restrict__ A, int N) {
  const int r = threadIdx.x >> 6, l = threadIdx.x & 63;
  const int node = blockIdx.x * 4 + r;
  if (node > N) return;
  if (node == N) {
    *(unsigned int*)(xb + (long)node * XSTR + 2 * l) = 0u;
    if (l < 4) *(unsigned int*)(xb + (long)node * XSTR + 128 + 2 * l) = 0u;
    *(unsigned int*)(A + (long)node * ASTR + 136 + 2 * l) = 0u;
    return;
  }
  const float2* xr = (const float2*)(x + (long)node * 130);
  float2 v = xr[l];
  *(ushort2*)(xb + (long)node * XSTR + 2 * l) = pk(v);
  if (l == 0) { float2 w = xr[64]; *(ushort2*)(xb + (long)node * XSTR + 128) = pk(w); }
  if (l >= 1 && l < 4) *(unsigned int*)(xb + (long)node * XSTR + 128 + 2 * l) = 0u;
}

// ---------- CSR build ----------
__global__ void zero_i_k(int* __restrict__ p, int n) {
  int i = blockIdx.x * 256 + threadIdx.x;
  if (i < n) p[i] = 0;
}
__global__ void count_k(const int* __restrict__ dst, int* __restrict__ degi, int E) {
  int i = blockIdx.x * 256 + threadIdx.x;
  if (i < E) atomicAdd(&degi[dst[i]], 1);
}
__global__ __launch_bounds__(256) void scan1_k(const int* __restrict__ degi,
                                               int* __restrict__ rowptr,
                                               int* __restrict__ bsum, int N) {
  __shared__ int sd[256];
  const int t = threadIdx.x;
  const int base = blockIdx.x * 1024 + t * 4;
  int v[4];
#pragma unroll
  for (int j = 0; j < 4; ++j) v[j] = (base + j < N) ? degi[base + j] : 0;
  const int tot = v[0] + v[1] + v[2] + v[3];
  sd[t] = tot;
  __syncthreads();
  for (int off = 1; off < 256; off <<= 1) {
    int o = (t >= off) ? sd[t - off] : 0;
    __syncthreads();
    sd[t] += o;
    __syncthreads();
  }
  int e = sd[t] - tot;
#pragma unroll
  for (int j = 0; j < 4; ++j) {
    if (base + j < N) rowptr[base + j] = e;
    e += v[j];
  }
  if (t == 255) bsum[blockIdx.x] = sd[255];
}
__global__ __launch_bounds__(256) void scan2_k(int* __restrict__ bsum, int nb) {
  __shared__ int sd[256];
  const int t = threadIdx.x;
  const int v = (t < nb) ? bsum[t] : 0;
  sd[t] = v;
  __syncthreads();
  for (int off = 1; off < 256; off <<= 1) {
    int o = (t >= off) ? sd[t - off] : 0;
    __syncthreads();
    sd[t] += o;
    __syncthreads();
  }
  if (t < nb) bsum[t] = sd[t] - v;
}
__global__ void scan3_k(int* __restrict__ rowptr, int* __restrict__ cursor,
                        const int* __restrict__ bsum, int N, int E) {
  int i = blockIdx.x * 256 + threadIdx.x;
  if (i < N) {
    int v = rowptr[i] + bsum[i >> 10];
    rowptr[i] = v;
    cursor[i] = v;
  } else if (i == N) {
    rowptr[N] = E;
  }
}
__global__ void fill_k(const int* __restrict__ src, const int* __restrict__ dst,
                       int* __restrict__ cursor, int* __restrict__ nbr, int E) {
  int i = blockIdx.x * 256 + threadIdx.x;
  if (i < E) {
    int p = atomicAdd(&cursor[dst[i]], 1);
    nbr[p] = src[i];
  }
}

// ---------- gather-mean: 4 nodes per wave, branchless predicated gather ----------
// Gathers bf16 rows from src + idx*SSTR + SOFF (64 dwords = 128 elems via lanes;
// EXTRA adds the dword at +128 = elems 128,129, broadcast-loaded by all lanes).
// Out-of-range slots load sentinel row idx=N (all zeros). Mean written to
// A + gid*ASTR + [0:128) (+ EXTRA: elems 128,129 and zero pad to 136).
template<int SSTR, int SOFF, bool EXTRA>
__global__ __launch_bounds__(256) void spmm_k(const unsigned short* __restrict__ src,
                                              const int* __restrict__ rowptr,
                                              const int* __restrict__ nbr,
                                              unsigned short* __restrict__ A, int N) {
  constexpr int JCH = EXTRA ? 4 : 8;   // neighbor chunk per epoch
  const int w = threadIdx.x >> 6, lane = threadIdx.x & 63;
  const int nb = blockIdx.x * 16 + w * 4;
  if (nb >= N) return;

  int rp = 0;
  if (lane <= 4 && nb + lane <= N) rp = rowptr[nb + lane];
  int d[4], r0[4], myn[4];
  float2 a[4], b[4];
#pragma unroll
  for (int r = 0; r < 4; ++r) {
    r0[r] = __shfl(rp, r, 64);
    const int r1 = __shfl(rp, r + 1, 64);
    d[r] = (nb + r < N) ? (r1 - r0[r]) : 0;
    a[r] = make_float2(0.f, 0.f);
    b[r] = make_float2(0.f, 0.f);
    myn[r] = N;
    if (lane < min(d[r], 64)) myn[r] = nbr[r0[r] + lane];
  }
  const int dm = max(max(d[0], d[1]), max(d[2], d[3]));

  if (dm <= 64) {
    for (int e0 = 0; e0 < dm; e0 += JCH) {
      unsigned int u[4][JCH], wv[4][JCH];
#pragma unroll
      for (int j = 0; j < JCH; ++j) {
#pragma unroll
        for (int r = 0; r < 4; ++r) {
          const int e = e0 + j;
          const int idx = (e < d[r]) ? __shfl(myn[r], e, 64) : N;
          const unsigned short* p = src + (long)idx * SSTR + SOFF;
          u[r][j] = *(const unsigned int*)(p + 2 * lane);
          if (EXTRA) wv[r][j] = *(const unsigned int*)(p + 128);
        }
      }
#pragma unroll
      for (int r = 0; r < 4; ++r)
#pragma unroll
        for (int j = 0; j < JCH; ++j) {
          a[r].x += bf2f(u[r][j] & 0xffffu);
          a[r].y += bf2f(u[r][j] >> 16);
          if (EXTRA) {
            b[r].x += bf2f(wv[r][j] & 0xffffu);
            b[r].y += bf2f(wv[r][j] >> 16);
          }
        }
    }
  } else {  // rare huge-degree fallback
    for (int r = 0; r < 4; ++r) {
      for (int base = r0[r]; base < r0[r] + d[r]; base += 64) {
        const int cnt = min(64, r0[r] + d[r] - base);
        const int mn = (lane < cnt) ? nbr[base + lane] : N;
        for (int e = 0; e < cnt; ++e) {
          const unsigned short* p = src + (long)__shfl(mn, e, 64) * SSTR + SOFF;
          const unsigned int uu = *(const unsigned int*)(p + 2 * lane);
          a[r].x += bf2f(uu & 0xffffu);
          a[r].y += bf2f(uu >> 16);
          if (EXTRA) {
            const unsigned int ww = *(const unsigned int*)(p + 128);
            b[r].x += bf2f(ww & 0xffffu);
            b[r].y += bf2f(ww >> 16);
          }
        }
      }
    }
  }

#pragma unroll
  for (int r = 0; r < 4; ++r) {
    if (nb + r < N) {
      const float inv = 1.0f / fmaxf((float)d[r], 1.0f);
      float2 m; m.x = a[r].x * inv; m.y = a[r].y * inv;
      unsigned short* Ar = A + (long)(nb + r) * ASTR;
      *(ushort2*)(Ar + 2 * lane) = pk(m);
      if (EXTRA) {
        if (lane == 0) {
          float2 mb; mb.x = b[r].x * inv; mb.y = b[r].y * inv;
          *(ushort2*)(Ar + 128) = pk(mb);
        }
        if (lane >= 1 && lane < 4) *(unsigned int*)(Ar + 128 + 2 * lane) = 0u;
      }
    }
  }
}

// ---------- GEMM + bias + BN + ReLU ----------
// A-tile row staged from two bf16 sources: chunks [0,C0) from S0 (stride ST0),
// [C0,C0+C1) from S1 (stride ST1), rest zeros. KP = KC*32.
template<int KC, int C0, int C1, int ST0, int ST1, bool L2MODE>
__global__ __launch_bounds__(256) void gemm_k(
    const unsigned short* __restrict__ S0, const unsigned short* __restrict__ S1,
    const unsigned short* __restrict__ wpk, const float* __restrict__ bias,
    const float* __restrict__ sc, const float* __restrict__ tc,
    void* __restrict__ out, int N) {
  constexpr int KP = KC * 32;
  constexpr int LDA = KP + 8;
  __shared__ __align__(16) unsigned short a_s[64][LDA];
  const int tid = threadIdx.x;
  const int node0 = blockIdx.x * 64;

  {
    const int row = tid >> 2, t4 = tid & 3;
    const int node = node0 + row;
#pragma unroll
    for (int i = 0; i < KC; ++i) {
      const int c = t4 + 4 * i;
      v8s v = {0, 0, 0, 0, 0, 0, 0, 0};
      if (node < N) {
        if (c < C0) v = *(const v8s*)(S0 + (long)node * ST0 + 8 * c);
        else if (c < C0 + C1) v = *(const v8s*)(S1 + (long)node * ST1 + 8 * (c - C0));
      }
      *(v8s*)&a_s[row][c * 8] = v;
    }
  }
  __syncthreads();

  const int wave = tid >> 6, lane = tid & 63;
  const int quad = lane >> 4, l16 = lane & 15;
  const int nt0 = wave * 2;
  v4f acc[4][2];
#pragma unroll
  for (int mt = 0; mt < 4; ++mt)
#pragma unroll
    for (int nt = 0; nt < 2; ++nt) acc[mt][nt] = (v4f){0.f, 0.f, 0.f, 0.f};

#pragma unroll
  for (int kc = 0; kc < KC; ++kc) {
    v8s bf[2];
#pragma unroll
    for (int nt = 0; nt < 2; ++nt) {
      const int n = (nt0 + nt) * 16 + l16;
      bf[nt] = *(const v8s*)(wpk + kc * 4096 + n * 32 + quad * 8);
    }
#pragma unroll
    for (int mt = 0; mt < 4; ++mt) {
      v8s af = *(const v8s*)(&a_s[mt * 16 + l16][kc * 32 + quad * 8]);
      acc[mt][0] = __builtin_amdgcn_mfma_f32_16x16x32_bf16(af, bf[0], acc[mt][0], 0, 0, 0);
      acc[mt][1] = __builtin_amdgcn_mfma_f32_16x16x32_bf16(af, bf[1], acc[mt][1], 0, 0, 0);
    }
  }

#pragma unroll
  for (int nt = 0; nt < 2; ++nt) {
    const int col = (nt0 + nt) * 16 + l16;
    const float bj = bias[col], sj = sc[col], tj = tc[col];
#pragma unroll
    for (int mt = 0; mt < 4; ++mt) {
#pragma unroll
      for (int r = 0; r < 4; ++r) {
        const int row = node0 + mt * 16 + quad * 4 + r;
        if (row < N) {
          float v = fmaxf((acc[mt][nt][r] + bj) * sj + tj, 0.f);
          if (L2MODE) ((float*)out)[(long)row * 128 + col] = v;
          else ((unsigned short*)out)[(long)row * ASTR + 136 + col] = f2bf(v);
        }
      }
    }
  }
}

extern "C" void kernel_launch(void* const* d_in, const int* in_sizes, int n_in,
                              void* d_out, int out_size, void* d_ws, size_t ws_size,
                              hipStream_t stream) {
  const float* x   = (const float*)d_in[0];
  const int*   ei  = (const int*)d_in[1];
  const float* W1l = (const float*)d_in[2];
  const float* b1  = (const float*)d_in[3];
  const float* W1r = (const float*)d_in[4];
  const float* g1  = (const float*)d_in[5];
  const float* be1 = (const float*)d_in[6];
  const float* rm1 = (const float*)d_in[7];
  const float* rv1 = (const float*)d_in[8];
  const float* W2l = (const float*)d_in[9];
  const float* b2  = (const float*)d_in[10];
  const float* W2r = (const float*)d_in[11];
  const float* g2  = (const float*)d_in[12];
  const float* be2 = (const float*)d_in[13];
  const float* rm2 = (const float*)d_in[14];
  const float* rv2 = (const float*)d_in[15];

  const int E = in_sizes[1] / 2;
  const int N = in_sizes[0] / 130;
  const int* src = ei;
  const int* dst = ei + E;

  // workspace carve
  unsigned short* A  = (unsigned short*)d_ws;          // (N+1)*272 bf16
  unsigned short* xb = A + (size_t)(N + 1) * ASTR;     // (N+1)*136 bf16
  unsigned short* wpk1 = xb + (size_t)(N + 1) * XSTR;  // 9*4096
  unsigned short* wpk2 = wpk1 + 9 * 4096;              // 8*4096
  float* s1 = (float*)(wpk2 + 8 * 4096);
  float* t1 = s1 + 128;
  float* s2 = t1 + 128;
  float* t2 = s2 + 128;
  int* degi   = (int*)(t2 + 128);   // N (reused as cursor)
  int* rowptr = degi + N;           // N+1
  int* bsum   = rowptr + N + 1;     // 256
  int* nbr    = bsum + 256;         // E

  hipLaunchKernelGGL(bn_fold_k, dim3(1), dim3(128), 0, stream,
                     g1, be1, rm1, rv1, g2, be2, rm2, rv2, s1, t1, s2, t2);
  hipLaunchKernelGGL((pack_w_k<130, 136, 9>), dim3(144), dim3(256), 0, stream, W1l, W1r, wpk1);
  hipLaunchKernelGGL((pack_w_k<128, 128, 8>), dim3(128), dim3(256), 0, stream, W2l, W2r, wpk2);
  hipLaunchKernelGGL(xb_k, dim3((N + 4) / 4), dim3(256), 0, stream, x, xb, A, N);

  // CSR build
  hipLaunchKernelGGL(zero_i_k, dim3((N + 255) / 256), dim3(256), 0, stream, degi, N);
  hipLaunchKernelGGL(count_k, dim3((E + 255) / 256), dim3(256), 0, stream, dst, degi, E);
  const int nb = (N + 1023) / 1024;
  hipLaunchKernelGGL(scan1_k, dim3(nb), dim3(256), 0, stream, degi, rowptr, bsum, N);
  hipLaunchKernelGGL(scan2_k, dim3(1), dim3(256), 0, stream, bsum, nb);
  hipLaunchKernelGGL(scan3_k, dim3((N + 256) / 256), dim3(256), 0, stream,
                     rowptr, degi, bsum, N, E);
  hipLaunchKernelGGL(fill_k, dim3((E + 255) / 256), dim3(256), 0, stream,
                     src, dst, degi, nbr, E);

  const int nsb = (N + 15) / 16;
  const int ngb = (N + 63) / 64;

  // layer 1: mean from xb -> A[0:136); gemm1 stages [A mean | xb root], h1 -> A[136:264)
  hipLaunchKernelGGL((spmm_k<XSTR, 0, true>), dim3(nsb), dim3(256), 0, stream,
                     xb, rowptr, nbr, A, N);
  hipLaunchKernelGGL((gemm_k<9, 17, 17, ASTR, XSTR, false>), dim3(ngb), dim3(256), 0, stream,
                     A, xb, wpk1, b1, s1, t1, (void*)A, N);
  // layer 2: mean2 from A h1-slot -> A[0:128); gemm2 stages [A mean2 | A h1] -> d_out fp32
  hipLaunchKernelGGL((spmm_k<ASTR, 136, false>), dim3(nsb), dim3(256), 0, stream,
                     A, rowptr, nbr, A, N);
  hipLaunchKernelGGL((gemm_k<8, 16, 16, ASTR, ASTR, true>), dim3(ngb), dim3(256), 0, stream,
                     A, A + 136, wpk2, b2, s2, t2, d_out, N);
}